// Round 7
// baseline (603.207 us; speedup 1.0000x reference)
//
#include <hip/hip_runtime.h>
#include <hip/hip_bf16.h>
#include <math.h>
#include <stdint.h>

#define TPB 256
#define NCB 32   // clusters per agg block
#define SAGG_LD 68    // padded LDS stride for s_agg rows (64 + 4)
#define SMID_LD 132   // padded LDS stride for s_mid rows (128 + 4)

typedef float f32x4 __attribute__((ext_vector_type(4)));
typedef short bf16x8 __attribute__((ext_vector_type(8)));

__device__ inline unsigned int bf16bits(float f)
{
    __hip_bfloat16 b = __float2bfloat16(f);
    return (unsigned int)(*(unsigned short*)&b);
}

__device__ inline unsigned int bfpack(float lo, float hi)
{
    return bf16bits(lo) | (bf16bits(hi) << 16);
}

// ---------------------------------------------------------------------------
// Sort stage 1: histogram of labels
// ---------------------------------------------------------------------------
__global__ __launch_bounds__(TPB) void hist_kernel(
    const int* __restrict__ labels, int* __restrict__ counts, int n)
{
    int i = blockIdx.x * TPB + threadIdx.x;
    if (i < n) atomicAdd(&counts[labels[i]], 1);
}

// ---------------------------------------------------------------------------
// Parallel scan over C bins, 3 kernels.
// ---------------------------------------------------------------------------
__global__ __launch_bounds__(256) void scan_local(
    const int* __restrict__ counts, int* __restrict__ off,
    int* __restrict__ bsum, int C)
{
    __shared__ int sh[256];
    int t = threadIdx.x;
    int i = blockIdx.x * 256 + t;
    int v = (i < C) ? counts[i] : 0;
    sh[t] = v;
    __syncthreads();
    for (int d = 1; d < 256; d <<= 1) {
        int u = (t >= d) ? sh[t - d] : 0;
        __syncthreads();
        sh[t] += u;
        __syncthreads();
    }
    if (i < C) off[i] = sh[t] - v;          // local exclusive prefix
    if (t == 255) bsum[blockIdx.x] = sh[255];
}

__global__ __launch_bounds__(256) void scan_base(
    int* __restrict__ bsum, int* __restrict__ off, int nb, int C)
{
    __shared__ int sh[256];
    int t = threadIdx.x;
    int v = (t < nb) ? bsum[t] : 0;
    sh[t] = v;
    __syncthreads();
    for (int d = 1; d < 256; d <<= 1) {
        int u = (t >= d) ? sh[t - d] : 0;
        __syncthreads();
        sh[t] += u;
        __syncthreads();
    }
    if (t < nb) bsum[t] = sh[t] - v;        // exclusive base per block
    if (t == 255) off[C] = sh[255];         // total == n
}

__global__ __launch_bounds__(256) void scan_apply(
    int* __restrict__ off, int* __restrict__ cursor,
    const int* __restrict__ bsum, int C)
{
    int i = blockIdx.x * 256 + threadIdx.x;
    if (i < C) {
        int v = off[i] + bsum[blockIdx.x];
        off[i] = v;
        cursor[i] = v;
    }
}

// ---------------------------------------------------------------------------
// Stage 1: per-point MLP.
// R4 (kept): scalar attn + L0/L1; L3 (32->64) via mfma_f32_16x16x32_bf16:
//   A: m = l&15, k = (l>>4)*8 + i      D: col = l&15, row = (l>>4)*4 + q
// R6: edge-L2 (16->32) via MFMA too, but UNLIKE R5:
//   - attention stays scalar (R5's attn-MFMA lengthened the critical chain)
//   - LDS stays 16 rows/wave (16KB total, occupancy preserved at R4 level):
//     rows 0-7 h2 pairs + rows 8-15 zeros (K-pad) -> L2 B operand;
//     after ALL L2 B-reads are in regs, h3 pair-writes overwrite rows 0-15
//     (D-layout direct), then L3 reads them. Same-wave DS ops execute in
//     order (pipe order covers both the anti-dep and the flow-dep);
//     sched_barrier(0) pins compiler instruction motion at the two hazards.
// ---------------------------------------------------------------------------
__global__ __launch_bounds__(TPB, 4) void point_mlp_kernel(
    const float* __restrict__ pf, const int* __restrict__ labels,
    const float* __restrict__ centers, const float* __restrict__ points,
    const float* __restrict__ we0, const float* __restrict__ be0,
    const float* __restrict__ we1, const float* __restrict__ be1,
    const float* __restrict__ we2, const float* __restrict__ be2,
    const float* __restrict__ we3, const float* __restrict__ be3,
    const float* __restrict__ wa0, const float* __restrict__ ba0,
    const float* __restrict__ wa1, const float* __restrict__ ba1,
    int* __restrict__ cursor, unsigned short* __restrict__ tsort, int n)
{
    __shared__ unsigned int s_stage[4][16][64];   // 16 KB

    int tid  = threadIdx.x;
    int lane = tid & 63;
    int w    = tid >> 6;
    int lg   = lane >> 4;     // 0..3
    int lm   = lane & 15;     // 0..15
    int pbase = blockIdx.x * TPB + w * 64;   // first point of this wave

    int i0 = blockIdx.x * TPB + tid;
    int i  = (i0 < n) ? i0 : (n - 1);        // clamp: tail lanes compute junk

    float x[11];
    const float4* pf4 = (const float4*)pf;
    float4 p0 = pf4[(size_t)i * 2 + 0];
    float4 p1 = pf4[(size_t)i * 2 + 1];
    x[0] = p0.x; x[1] = p0.y; x[2] = p0.z; x[3] = p0.w;
    x[4] = p1.x; x[5] = p1.y; x[6] = p1.z; x[7] = p1.w;

    int lbl = labels[i];
    x[8]  = centers[lbl * 3 + 0] - points[(size_t)i * 3 + 0];
    x[9]  = centers[lbl * 3 + 1] - points[(size_t)i * 3 + 1];
    x[10] = centers[lbl * 3 + 2] - points[(size_t)i * 3 + 2];

    // claim sorted slot early; latency overlaps the MLP compute below
    int pos = 0;
    if (i0 < n) pos = atomicAdd(&cursor[lbl], 1);

    // attention MLP: 11 -> 64 relu -> 1 sigmoid (scalar, R4-proven)
    float s = ba1[0];
#pragma unroll
    for (int j = 0; j < 64; j++) {
        float aj = ba0[j];
#pragma unroll
        for (int k = 0; k < 11; k++) aj = fmaf(x[k], wa0[k * 64 + j], aj);
        aj = fmaxf(aj, 0.f);
        s = fmaf(aj, wa1[j], s);
    }
    float gate = 1.f / (1.f + __expf(-s));

    // edge MLP L0/L1 scalar
    float h1[8];
#pragma unroll
    for (int j = 0; j < 8; j++) {
        float v = be0[j];
#pragma unroll
        for (int k = 0; k < 11; k++) v = fmaf(x[k], we0[k * 8 + j], v);
        h1[j] = fmaxf(v, 0.f);
    }
    float h2[16];
#pragma unroll
    for (int j = 0; j < 16; j++) {
        float v = be1[j];
#pragma unroll
        for (int k = 0; k < 8; k++) v = fmaf(h1[k], we1[k * 16 + j], v);
        h2[j] = fmaxf(v, 0.f);
    }

    // stage h2 pairs rows 0..7, zero-pad rows 8..15 (K pad to 32)
#pragma unroll
    for (int r = 0; r < 8; r++)
        s_stage[w][r][lane] = bfpack(h2[2 * r], h2[2 * r + 1]);
#pragma unroll
    for (int r = 8; r < 16; r++)
        s_stage[w][r][lane] = 0u;

    // A-fragments for L2 (we2 is [16][32]; zeros for k >= 16)
    bf16x8 a_l2[2];
#pragma unroll
    for (int mt = 0; mt < 2; mt++) {
        union { unsigned int u[4]; bf16x8 v; } au;
#pragma unroll
        for (int ii = 0; ii < 4; ii++) {
            int k0 = lg * 8 + 2 * ii;
            int j  = mt * 16 + lm;
            unsigned int u = 0;
            if (k0 < 16)     u  = bf16bits(we2[k0 * 32 + j]);
            if (k0 + 1 < 16) u |= bf16bits(we2[(k0 + 1) * 32 + j]) << 16;
            au.u[ii] = u;
        }
        a_l2[mt] = au.v;
    }

    // A-fragments for L3 (we3 is [32][64], full K)
    bf16x8 a_l3[4];
#pragma unroll
    for (int mt = 0; mt < 4; mt++) {
        union { unsigned int u[4]; bf16x8 v; } au;
#pragma unroll
        for (int ii = 0; ii < 4; ii++) {
            int k0 = lg * 8 + 2 * ii;
            int j  = mt * 16 + lm;
            au.u[ii] = bfpack(we3[k0 * 64 + j], we3[(k0 + 1) * 64 + j]);
        }
        a_l3[mt] = au.v;
    }

    // ---- L2 via MFMA: read ALL B-fragments first (rows 0-15 = h2+pad) ----
    unsigned int bu_all[4][4];
#pragma unroll
    for (int nt = 0; nt < 4; nt++) {
#pragma unroll
        for (int ii = 0; ii < 4; ii++)
            bu_all[nt][ii] = s_stage[w][lg * 4 + ii][nt * 16 + lm];
    }
    __builtin_amdgcn_sched_barrier(0);   // keep h3 writes below these reads

    unsigned int h3w[4][2][2];           // [nt][mt][pair]
#pragma unroll
    for (int nt = 0; nt < 4; nt++) {
        union { unsigned int u[4]; bf16x8 v; } bu;
#pragma unroll
        for (int ii = 0; ii < 4; ii++) bu.u[ii] = bu_all[nt][ii];
#pragma unroll
        for (int mt = 0; mt < 2; mt++) {
            f32x4 acc = {0.f, 0.f, 0.f, 0.f};
            acc = __builtin_amdgcn_mfma_f32_16x16x32_bf16(a_l2[mt], bu.v, acc, 0, 0, 0);
            const float4 b2 = *(const float4*)&be2[mt * 16 + lg * 4];
            float d0 = fmaxf(acc[0] + b2.x, 0.f);
            float d1 = fmaxf(acc[1] + b2.y, 0.f);
            float d2 = fmaxf(acc[2] + b2.z, 0.f);
            float d3 = fmaxf(acc[3] + b2.w, 0.f);
            h3w[nt][mt][0] = bfpack(d0, d1);
            h3w[nt][mt][1] = bfpack(d2, d3);
        }
    }

    // write h3 pairs into rows 0-15 (overwrite; all reads already done)
#pragma unroll
    for (int nt = 0; nt < 4; nt++) {
#pragma unroll
        for (int mt = 0; mt < 2; mt++) {
            s_stage[w][mt * 8 + lg * 2 + 0][nt * 16 + lm] = h3w[nt][mt][0];
            s_stage[w][mt * 8 + lg * 2 + 1][nt * 16 + lm] = h3w[nt][mt][1];
        }
    }
    __builtin_amdgcn_sched_barrier(0);   // keep L3 reads below these writes

    // ---- L3 via MFMA (R4 epilogue) ----
#pragma unroll
    for (int nt = 0; nt < 4; nt++) {
        int   spt   = nt * 16 + lm;
        float g     = __shfl(gate, spt, 64);
        int   ppos  = __shfl(pos,  spt, 64);
        bool  valid = (pbase + spt) < n;

        union { unsigned int u[4]; bf16x8 v; } bu;
#pragma unroll
        for (int ii = 0; ii < 4; ii++) bu.u[ii] = s_stage[w][lg * 4 + ii][spt];

#pragma unroll
        for (int mt = 0; mt < 4; mt++) {
            f32x4 acc = {0.f, 0.f, 0.f, 0.f};
            acc = __builtin_amdgcn_mfma_f32_16x16x32_bf16(a_l3[mt], bu.v, acc, 0, 0, 0);
            int jb = mt * 16 + lg * 4;
            const float4 bias = *(const float4*)&be3[jb];
            float v0 = fmaxf(acc[0] + bias.x, 0.f) * g;
            float v1 = fmaxf(acc[1] + bias.y, 0.f) * g;
            float v2 = fmaxf(acc[2] + bias.z, 0.f) * g;
            float v3 = fmaxf(acc[3] + bias.w, 0.f) * g;
            if (valid) {
                unsigned int d0 = bfpack(v0, v1);
                unsigned int d1 = bfpack(v2, v3);
                *(uint2*)((unsigned int*)tsort + (size_t)ppos * 32 + (jb >> 1)) =
                    make_uint2(d0, d1);
            }
        }
    }
}

// ---------------------------------------------------------------------------
// Stage 2: aggregation + output MLP (unchanged from R3).
// ---------------------------------------------------------------------------
__global__ __launch_bounds__(TPB) void agg_outmlp_kernel(
    const unsigned short* __restrict__ tsort,
    const int* __restrict__ off,
    const float* __restrict__ wo0, const float* __restrict__ bo0,
    const float* __restrict__ wo1, const float* __restrict__ bo1,
    float* __restrict__ out)
{
    __shared__ float s_agg[NCB * SAGG_LD];   // ~8.7 KB
    __shared__ float s_mid[NCB * SMID_LD];   // ~16.9 KB
    int tid = threadIdx.x;
    int c0 = blockIdx.x * NCB;

    // phase A: aggregate
    {
        int lane  = tid & 63;
        int w     = tid >> 6;
        int rlane = lane >> 3;           // 0..7 : which row of the 8-row group
        int word  = lane & 7;            // 0..7 : uint4 index within 128B row
        const uint4* t128 = (const uint4*)tsort;   // one row = 8 x uint4
#define BF_LO(u) (__uint_as_float((u) << 16))
#define BF_HI(u) (__uint_as_float((u) & 0xffff0000u))
        for (int lc = w * 8; lc < w * 8 + 8; lc++) {
            int rb = off[c0 + lc];
            int re = off[c0 + lc + 1];
            float a[8];
#pragma unroll
            for (int q = 0; q < 8; q++) a[q] = 0.f;
            for (int r = rb; r < re; r += 16) {
                int r0 = r + rlane;
                int r1 = r + 8 + rlane;
                uint4 v0 = make_uint4(0u, 0u, 0u, 0u);
                uint4 v1 = make_uint4(0u, 0u, 0u, 0u);
                if (r0 < re) v0 = t128[(size_t)r0 * 8 + word];
                if (r1 < re) v1 = t128[(size_t)r1 * 8 + word];
                a[0] += BF_LO(v0.x) + BF_LO(v1.x);
                a[1] += BF_HI(v0.x) + BF_HI(v1.x);
                a[2] += BF_LO(v0.y) + BF_LO(v1.y);
                a[3] += BF_HI(v0.y) + BF_HI(v1.y);
                a[4] += BF_LO(v0.z) + BF_LO(v1.z);
                a[5] += BF_HI(v0.z) + BF_HI(v1.z);
                a[6] += BF_LO(v0.w) + BF_LO(v1.w);
                a[7] += BF_HI(v0.w) + BF_HI(v1.w);
            }
            // reduce the 8 row-groups (lanes differing in bits 3..5)
#pragma unroll
            for (int m = 8; m < 64; m <<= 1) {
#pragma unroll
                for (int q = 0; q < 8; q++) a[q] += __shfl_xor(a[q], m, 64);
            }
            if (rlane == 0) {
                // lane 'word' holds features word*8 .. word*8+7
                *(float4*)&s_agg[lc * SAGG_LD + word * 8 + 0] =
                    make_float4(a[0], a[1], a[2], a[3]);
                *(float4*)&s_agg[lc * SAGG_LD + word * 8 + 4] =
                    make_float4(a[4], a[5], a[6], a[7]);
            }
        }
#undef BF_LO
#undef BF_HI
    }
    __syncthreads();

    // phase B: mid[NCB][128] = relu(agg @ wo0 + bo0)
    {
        int mg = tid & 15;
        int cg = tid >> 4;
        int m0 = mg * 8;
        float acc[2][8];
#pragma unroll
        for (int mi = 0; mi < 8; mi++) {
            float b = bo0[m0 + mi];
            acc[0][mi] = b;
            acc[1][mi] = b;
        }
        for (int k = 0; k < 64; k += 4) {
            float4 a0 = *(const float4*)&s_agg[(cg * 2 + 0) * SAGG_LD + k];
            float4 a1 = *(const float4*)&s_agg[(cg * 2 + 1) * SAGG_LD + k];
            float av0[4] = {a0.x, a0.y, a0.z, a0.w};
            float av1[4] = {a1.x, a1.y, a1.z, a1.w};
#pragma unroll
            for (int q = 0; q < 4; q++) {
                float4 wlo = *(const float4*)&wo0[(k + q) * 128 + m0];
                float4 whi = *(const float4*)&wo0[(k + q) * 128 + m0 + 4];
                float wv[8] = {wlo.x, wlo.y, wlo.z, wlo.w,
                               whi.x, whi.y, whi.z, whi.w};
#pragma unroll
                for (int mi = 0; mi < 8; mi++) {
                    acc[0][mi] = fmaf(av0[q], wv[mi], acc[0][mi]);
                    acc[1][mi] = fmaf(av1[q], wv[mi], acc[1][mi]);
                }
            }
        }
#pragma unroll
        for (int c = 0; c < 2; c++) {
            float4 lo = make_float4(fmaxf(acc[c][0], 0.f), fmaxf(acc[c][1], 0.f),
                                    fmaxf(acc[c][2], 0.f), fmaxf(acc[c][3], 0.f));
            float4 hi = make_float4(fmaxf(acc[c][4], 0.f), fmaxf(acc[c][5], 0.f),
                                    fmaxf(acc[c][6], 0.f), fmaxf(acc[c][7], 0.f));
            *(float4*)&s_mid[(cg * 2 + c) * SMID_LD + m0 + 0] = lo;
            *(float4*)&s_mid[(cg * 2 + c) * SMID_LD + m0 + 4] = hi;
        }
    }
    __syncthreads();

    // phase C: out[NCB][256] = relu(mid @ wo1 + bo1)
    {
        int mg = tid & 31;
        int cg = tid >> 5;
        int m0 = mg * 8;
        float acc[4][8];
#pragma unroll
        for (int mi = 0; mi < 8; mi++) {
            float b = bo1[m0 + mi];
            acc[0][mi] = b;
            acc[1][mi] = b;
            acc[2][mi] = b;
            acc[3][mi] = b;
        }
        for (int j = 0; j < 128; j += 4) {
            float4 a0 = *(const float4*)&s_mid[(cg * 4 + 0) * SMID_LD + j];
            float4 a1 = *(const float4*)&s_mid[(cg * 4 + 1) * SMID_LD + j];
            float4 a2 = *(const float4*)&s_mid[(cg * 4 + 2) * SMID_LD + j];
            float4 a3 = *(const float4*)&s_mid[(cg * 4 + 3) * SMID_LD + j];
            float av0[4] = {a0.x, a0.y, a0.z, a0.w};
            float av1[4] = {a1.x, a1.y, a1.z, a1.w};
            float av2[4] = {a2.x, a2.y, a2.z, a2.w};
            float av3[4] = {a3.x, a3.y, a3.z, a3.w};
#pragma unroll
            for (int q = 0; q < 4; q++) {
                float4 wlo = *(const float4*)&wo1[(j + q) * 256 + m0];
                float4 whi = *(const float4*)&wo1[(j + q) * 256 + m0 + 4];
                float wv[8] = {wlo.x, wlo.y, wlo.z, wlo.w,
                               whi.x, whi.y, whi.z, whi.w};
#pragma unroll
                for (int mi = 0; mi < 8; mi++) {
                    acc[0][mi] = fmaf(av0[q], wv[mi], acc[0][mi]);
                    acc[1][mi] = fmaf(av1[q], wv[mi], acc[1][mi]);
                    acc[2][mi] = fmaf(av2[q], wv[mi], acc[2][mi]);
                    acc[3][mi] = fmaf(av3[q], wv[mi], acc[3][mi]);
                }
            }
        }
#pragma unroll
        for (int c = 0; c < 4; c++) {
            float4 lo = make_float4(fmaxf(acc[c][0], 0.f), fmaxf(acc[c][1], 0.f),
                                    fmaxf(acc[c][2], 0.f), fmaxf(acc[c][3], 0.f));
            float4 hi = make_float4(fmaxf(acc[c][4], 0.f), fmaxf(acc[c][5], 0.f),
                                    fmaxf(acc[c][6], 0.f), fmaxf(acc[c][7], 0.f));
            size_t row = (size_t)(c0 + cg * 4 + c) * 256 + m0;
            *(float4*)&out[row + 0] = lo;
            *(float4*)&out[row + 4] = hi;
        }
    }
}

extern "C" void kernel_launch(void* const* d_in, const int* in_sizes, int n_in,
                              void* d_out, int out_size, void* d_ws, size_t ws_size,
                              hipStream_t stream)
{
    const float* pf      = (const float*)d_in[0];
    const int*   labels  = (const int*)d_in[1];
    const float* centers = (const float*)d_in[2];
    const float* points  = (const float*)d_in[3];
    const float* we0 = (const float*)d_in[4];
    const float* be0 = (const float*)d_in[5];
    const float* we1 = (const float*)d_in[6];
    const float* be1 = (const float*)d_in[7];
    const float* we2 = (const float*)d_in[8];
    const float* be2 = (const float*)d_in[9];
    const float* we3 = (const float*)d_in[10];
    const float* be3 = (const float*)d_in[11];
    const float* wa0 = (const float*)d_in[12];
    const float* ba0 = (const float*)d_in[13];
    const float* wa1 = (const float*)d_in[14];
    const float* ba1 = (const float*)d_in[15];
    const float* wo0 = (const float*)d_in[16];
    const float* bo0 = (const float*)d_in[17];
    const float* wo1 = (const float*)d_in[18];
    const float* bo1 = (const float*)d_in[19];
    float* out = (float*)d_out;

    int n = in_sizes[0] / 8;        // N points (2,000,000)
    int C = in_sizes[2] / 3;        // clusters (65,536)

    // workspace layout
    int* counts = (int*)d_ws;                   // C
    int* cursor = counts + C;                   // C
    int* off    = cursor + C;                   // C+1
    int* bsum   = off + C + 1;                  // <=256
    uintptr_t tb = ((uintptr_t)(bsum + 256) + 255) & ~(uintptr_t)255;
    unsigned short* tsort = (unsigned short*)tb; // n x 64 bf16, cluster-sorted

    hipMemsetAsync(counts, 0, (size_t)C * sizeof(int), stream);

    int pblocks = (n + TPB - 1) / TPB;
    int nb = (C + 255) / 256;                   // 256 scan blocks
    hist_kernel<<<pblocks, TPB, 0, stream>>>(labels, counts, n);
    scan_local<<<nb, 256, 0, stream>>>(counts, off, bsum, C);
    scan_base<<<1, 256, 0, stream>>>(bsum, off, nb, C);
    scan_apply<<<nb, 256, 0, stream>>>(off, cursor, bsum, C);

    point_mlp_kernel<<<pblocks, TPB, 0, stream>>>(
        pf, labels, centers, points,
        we0, be0, we1, be1, we2, be2, we3, be3,
        wa0, ba0, wa1, ba1, cursor, tsort, n);

    agg_outmlp_kernel<<<C / NCB, TPB, 0, stream>>>(
        tsort, off, wo0, bo0, wo1, bo1, out);
}

// Round 8
// 561.128 us; speedup vs baseline: 1.0750x; 1.0750x over previous
//
#include <hip/hip_runtime.h>
#include <hip/hip_bf16.h>
#include <math.h>
#include <stdint.h>

#define TPB 256
#define NCB 32   // clusters per agg block
#define SAGG_LD 68    // padded LDS stride for s_agg rows (64 + 4)
#define SMID_LD 132   // padded LDS stride for s_mid rows (128 + 4)

typedef float f32x4 __attribute__((ext_vector_type(4)));
typedef short bf16x8 __attribute__((ext_vector_type(8)));

__device__ inline unsigned int bf16bits(float f)
{
    __hip_bfloat16 b = __float2bfloat16(f);
    return (unsigned int)(*(unsigned short*)&b);
}

__device__ inline unsigned int bfpack(float lo, float hi)
{
    return bf16bits(lo) | (bf16bits(hi) << 16);
}

// ---------------------------------------------------------------------------
// Sort stage 1: histogram of labels
// ---------------------------------------------------------------------------
__global__ __launch_bounds__(TPB) void hist_kernel(
    const int* __restrict__ labels, int* __restrict__ counts, int n)
{
    int i = blockIdx.x * TPB + threadIdx.x;
    if (i < n) atomicAdd(&counts[labels[i]], 1);
}

// ---------------------------------------------------------------------------
// Parallel scan over C bins, 3 kernels.
// ---------------------------------------------------------------------------
__global__ __launch_bounds__(256) void scan_local(
    const int* __restrict__ counts, int* __restrict__ off,
    int* __restrict__ bsum, int C)
{
    __shared__ int sh[256];
    int t = threadIdx.x;
    int i = blockIdx.x * 256 + t;
    int v = (i < C) ? counts[i] : 0;
    sh[t] = v;
    __syncthreads();
    for (int d = 1; d < 256; d <<= 1) {
        int u = (t >= d) ? sh[t - d] : 0;
        __syncthreads();
        sh[t] += u;
        __syncthreads();
    }
    if (i < C) off[i] = sh[t] - v;          // local exclusive prefix
    if (t == 255) bsum[blockIdx.x] = sh[255];
}

__global__ __launch_bounds__(256) void scan_base(
    int* __restrict__ bsum, int* __restrict__ off, int nb, int C)
{
    __shared__ int sh[256];
    int t = threadIdx.x;
    int v = (t < nb) ? bsum[t] : 0;
    sh[t] = v;
    __syncthreads();
    for (int d = 1; d < 256; d <<= 1) {
        int u = (t >= d) ? sh[t - d] : 0;
        __syncthreads();
        sh[t] += u;
        __syncthreads();
    }
    if (t < nb) bsum[t] = sh[t] - v;        // exclusive base per block
    if (t == 255) off[C] = sh[255];         // total == n
}

__global__ __launch_bounds__(256) void scan_apply(
    int* __restrict__ off, int* __restrict__ cursor,
    const int* __restrict__ bsum, int C)
{
    int i = blockIdx.x * 256 + threadIdx.x;
    if (i < C) {
        int v = off[i] + bsum[blockIdx.x];
        off[i] = v;
        cursor[i] = v;
    }
}

// ---------------------------------------------------------------------------
// Stage 1: per-point MLP — EXACT R4 (proven 206us). R5 (attn+L2 MFMA) and
// R6 (L2 MFMA only) both regressed: extra fragment-build VALU + LDS round
// trips + scheduling walls outweighed the removed scalar FMAs. Scalar attn/
// L0/L1/L2 + MFMA L3 is the empirical optimum for this structure.
//   A: m = l&15, k = (l>>4)*8 + i      D: col = l&15, row = (l>>4)*4 + q
// ---------------------------------------------------------------------------
__global__ __launch_bounds__(TPB, 4) void point_mlp_kernel(
    const float* __restrict__ pf, const int* __restrict__ labels,
    const float* __restrict__ centers, const float* __restrict__ points,
    const float* __restrict__ we0, const float* __restrict__ be0,
    const float* __restrict__ we1, const float* __restrict__ be1,
    const float* __restrict__ we2, const float* __restrict__ be2,
    const float* __restrict__ we3, const float* __restrict__ be3,
    const float* __restrict__ wa0, const float* __restrict__ ba0,
    const float* __restrict__ wa1, const float* __restrict__ ba1,
    int* __restrict__ cursor, unsigned short* __restrict__ tsort, int n)
{
    __shared__ unsigned int s_h3[4][16][64];   // 16KB: [wave][kk][pt-in-wave]

    int i0 = blockIdx.x * TPB + threadIdx.x;
    int i  = (i0 < n) ? i0 : (n - 1);          // clamp: tail lanes compute junk

    float x[11];
    const float4* pf4 = (const float4*)pf;
    float4 p0 = pf4[(size_t)i * 2 + 0];
    float4 p1 = pf4[(size_t)i * 2 + 1];
    x[0] = p0.x; x[1] = p0.y; x[2] = p0.z; x[3] = p0.w;
    x[4] = p1.x; x[5] = p1.y; x[6] = p1.z; x[7] = p1.w;

    int lbl = labels[i];
    x[8]  = centers[lbl * 3 + 0] - points[(size_t)i * 3 + 0];
    x[9]  = centers[lbl * 3 + 1] - points[(size_t)i * 3 + 1];
    x[10] = centers[lbl * 3 + 2] - points[(size_t)i * 3 + 2];

    // claim sorted slot early; latency overlaps the MLP compute below
    int pos = 0;
    if (i0 < n) pos = atomicAdd(&cursor[lbl], 1);

    // attention MLP: 11 -> 64 relu -> 1 sigmoid
    float s = ba1[0];
#pragma unroll
    for (int j = 0; j < 64; j++) {
        float aj = ba0[j];
#pragma unroll
        for (int k = 0; k < 11; k++) aj = fmaf(x[k], wa0[k * 64 + j], aj);
        aj = fmaxf(aj, 0.f);
        s = fmaf(aj, wa1[j], s);
    }
    float gate = 1.f / (1.f + __expf(-s));

    // edge MLP: 11 -> 8 -> 16 -> 32
    float h1[8];
#pragma unroll
    for (int j = 0; j < 8; j++) {
        float v = be0[j];
#pragma unroll
        for (int k = 0; k < 11; k++) v = fmaf(x[k], we0[k * 8 + j], v);
        h1[j] = fmaxf(v, 0.f);
    }
    float h2[16];
#pragma unroll
    for (int j = 0; j < 16; j++) {
        float v = be1[j];
#pragma unroll
        for (int k = 0; k < 8; k++) v = fmaf(h1[k], we1[k * 16 + j], v);
        h2[j] = fmaxf(v, 0.f);
    }
    float h3[32];
#pragma unroll
    for (int j = 0; j < 32; j++) {
        float v = be2[j];
#pragma unroll
        for (int k = 0; k < 16; k++) v = fmaf(h2[k], we2[k * 32 + j], v);
        h3[j] = fmaxf(v, 0.f);
    }

    // ---- L3 via MFMA ----
    int lane = threadIdx.x & 63;
    int w    = threadIdx.x >> 6;
    int lg   = lane >> 4;     // 0..3
    int lm   = lane & 15;     // 0..15
    int pbase = blockIdx.x * TPB + w * 64;   // first point of this wave

    // stage own h3 as bf16 pairs: s_h3[w][kk][lane] = (h3[2kk], h3[2kk+1])
#pragma unroll
    for (int kk = 0; kk < 16; kk++) {
        s_h3[w][kk][lane] = bf16bits(h3[2 * kk]) | (bf16bits(h3[2 * kk + 1]) << 16);
    }

    // A-fragments (weights), one per M-tile of 16 j's
    bf16x8 afrag[4];
#pragma unroll
    for (int mt = 0; mt < 4; mt++) {
        union { unsigned int u[4]; bf16x8 v; } au;
#pragma unroll
        for (int ii = 0; ii < 4; ii++) {
            float w0 = we3[(lg * 8 + 2 * ii + 0) * 64 + mt * 16 + lm];
            float w1 = we3[(lg * 8 + 2 * ii + 1) * 64 + mt * 16 + lm];
            au.u[ii] = bf16bits(w0) | (bf16bits(w1) << 16);
        }
        afrag[mt] = au.v;
    }

#pragma unroll
    for (int nt = 0; nt < 4; nt++) {
        int   spt  = nt * 16 + lm;                 // source point-in-wave
        float g    = __shfl(gate, spt, 64);
        int   ppos = __shfl(pos,  spt, 64);
        bool  valid = (pbase + spt) < n;

        union { unsigned int u[4]; bf16x8 v; } bu;
#pragma unroll
        for (int ii = 0; ii < 4; ii++) bu.u[ii] = s_h3[w][lg * 4 + ii][spt];

#pragma unroll
        for (int mt = 0; mt < 4; mt++) {
            f32x4 acc = {0.f, 0.f, 0.f, 0.f};
            acc = __builtin_amdgcn_mfma_f32_16x16x32_bf16(afrag[mt], bu.v, acc, 0, 0, 0);
            int jb = mt * 16 + lg * 4;
            const float4 bias = *(const float4*)&be3[jb];
            float v0 = fmaxf(acc[0] + bias.x, 0.f) * g;
            float v1 = fmaxf(acc[1] + bias.y, 0.f) * g;
            float v2 = fmaxf(acc[2] + bias.z, 0.f) * g;
            float v3 = fmaxf(acc[3] + bias.w, 0.f) * g;
            if (valid) {
                unsigned int d0 = bfpack(v0, v1);
                unsigned int d1 = bfpack(v2, v3);
                *(uint2*)((unsigned int*)tsort + (size_t)ppos * 32 + (jb >> 1)) =
                    make_uint2(d0, d1);
            }
        }
    }
}

// ---------------------------------------------------------------------------
// Stage 2a: aggregation only (R7 split for per-phase counters). Writes the
// 64-float cluster aggregate into out[c*256 + 0..63] (stash region; each
// outmlp block reads its own rows before overwriting them, and kernel
// boundaries order the accesses).
// ---------------------------------------------------------------------------
__global__ __launch_bounds__(TPB) void agg_kernel(
    const unsigned short* __restrict__ tsort,
    const int* __restrict__ off,
    float* __restrict__ out)
{
    int tid = threadIdx.x;
    int c0 = blockIdx.x * NCB;
    int lane  = tid & 63;
    int w     = tid >> 6;
    int rlane = lane >> 3;           // 0..7 : which row of the 8-row group
    int word  = lane & 7;            // 0..7 : uint4 index within 128B row
    const uint4* t128 = (const uint4*)tsort;   // one row = 8 x uint4
#define BF_LO(u) (__uint_as_float((u) << 16))
#define BF_HI(u) (__uint_as_float((u) & 0xffff0000u))
    for (int lc = w * 8; lc < w * 8 + 8; lc++) {
        int rb = off[c0 + lc];
        int re = off[c0 + lc + 1];
        float a[8];
#pragma unroll
        for (int q = 0; q < 8; q++) a[q] = 0.f;
        for (int r = rb; r < re; r += 16) {
            int r0 = r + rlane;
            int r1 = r + 8 + rlane;
            uint4 v0 = make_uint4(0u, 0u, 0u, 0u);
            uint4 v1 = make_uint4(0u, 0u, 0u, 0u);
            if (r0 < re) v0 = t128[(size_t)r0 * 8 + word];
            if (r1 < re) v1 = t128[(size_t)r1 * 8 + word];
            a[0] += BF_LO(v0.x) + BF_LO(v1.x);
            a[1] += BF_HI(v0.x) + BF_HI(v1.x);
            a[2] += BF_LO(v0.y) + BF_LO(v1.y);
            a[3] += BF_HI(v0.y) + BF_HI(v1.y);
            a[4] += BF_LO(v0.z) + BF_LO(v1.z);
            a[5] += BF_HI(v0.z) + BF_HI(v1.z);
            a[6] += BF_LO(v0.w) + BF_LO(v1.w);
            a[7] += BF_HI(v0.w) + BF_HI(v1.w);
        }
        // reduce the 8 row-groups (lanes differing in bits 3..5)
#pragma unroll
        for (int m = 8; m < 64; m <<= 1) {
#pragma unroll
            for (int q = 0; q < 8; q++) a[q] += __shfl_xor(a[q], m, 64);
        }
        if (rlane == 0) {
            // lane 'word' holds features word*8 .. word*8+7
            size_t row = (size_t)(c0 + lc) * 256 + word * 8;
            *(float4*)&out[row + 0] = make_float4(a[0], a[1], a[2], a[3]);
            *(float4*)&out[row + 4] = make_float4(a[4], a[5], a[6], a[7]);
        }
    }
#undef BF_LO
#undef BF_HI
}

// ---------------------------------------------------------------------------
// Stage 2b: output MLP (R3 register-blocked phases B/C). Reads the stashed
// aggregates from out[c*256 + 0..63], then overwrites the full rows.
// ---------------------------------------------------------------------------
__global__ __launch_bounds__(TPB) void outmlp_kernel(
    const float* __restrict__ wo0, const float* __restrict__ bo0,
    const float* __restrict__ wo1, const float* __restrict__ bo1,
    float* __restrict__ out)
{
    __shared__ float s_agg[NCB * SAGG_LD];   // ~8.7 KB
    __shared__ float s_mid[NCB * SMID_LD];   // ~16.9 KB
    int tid = threadIdx.x;
    int c0 = blockIdx.x * NCB;

    // load stashed aggregates: 32 rows x 64 floats
    {
        int row = tid >> 3;        // 0..31
        int k0  = (tid & 7) * 8;   // 0,8,..,56
        float4 v0 = *(const float4*)&out[(size_t)(c0 + row) * 256 + k0];
        float4 v1 = *(const float4*)&out[(size_t)(c0 + row) * 256 + k0 + 4];
        *(float4*)&s_agg[row * SAGG_LD + k0 + 0] = v0;
        *(float4*)&s_agg[row * SAGG_LD + k0 + 4] = v1;
    }
    __syncthreads();

    // phase B: mid[NCB][128] = relu(agg @ wo0 + bo0)
    {
        int mg = tid & 15;
        int cg = tid >> 4;
        int m0 = mg * 8;
        float acc[2][8];
#pragma unroll
        for (int mi = 0; mi < 8; mi++) {
            float b = bo0[m0 + mi];
            acc[0][mi] = b;
            acc[1][mi] = b;
        }
        for (int k = 0; k < 64; k += 4) {
            float4 a0 = *(const float4*)&s_agg[(cg * 2 + 0) * SAGG_LD + k];
            float4 a1 = *(const float4*)&s_agg[(cg * 2 + 1) * SAGG_LD + k];
            float av0[4] = {a0.x, a0.y, a0.z, a0.w};
            float av1[4] = {a1.x, a1.y, a1.z, a1.w};
#pragma unroll
            for (int q = 0; q < 4; q++) {
                float4 wlo = *(const float4*)&wo0[(k + q) * 128 + m0];
                float4 whi = *(const float4*)&wo0[(k + q) * 128 + m0 + 4];
                float wv[8] = {wlo.x, wlo.y, wlo.z, wlo.w,
                               whi.x, whi.y, whi.z, whi.w};
#pragma unroll
                for (int mi = 0; mi < 8; mi++) {
                    acc[0][mi] = fmaf(av0[q], wv[mi], acc[0][mi]);
                    acc[1][mi] = fmaf(av1[q], wv[mi], acc[1][mi]);
                }
            }
        }
#pragma unroll
        for (int c = 0; c < 2; c++) {
            float4 lo = make_float4(fmaxf(acc[c][0], 0.f), fmaxf(acc[c][1], 0.f),
                                    fmaxf(acc[c][2], 0.f), fmaxf(acc[c][3], 0.f));
            float4 hi = make_float4(fmaxf(acc[c][4], 0.f), fmaxf(acc[c][5], 0.f),
                                    fmaxf(acc[c][6], 0.f), fmaxf(acc[c][7], 0.f));
            *(float4*)&s_mid[(cg * 2 + c) * SMID_LD + m0 + 0] = lo;
            *(float4*)&s_mid[(cg * 2 + c) * SMID_LD + m0 + 4] = hi;
        }
    }
    __syncthreads();

    // phase C: out[NCB][256] = relu(mid @ wo1 + bo1)
    {
        int mg = tid & 31;
        int cg = tid >> 5;
        int m0 = mg * 8;
        float acc[4][8];
#pragma unroll
        for (int mi = 0; mi < 8; mi++) {
            float b = bo1[m0 + mi];
            acc[0][mi] = b;
            acc[1][mi] = b;
            acc[2][mi] = b;
            acc[3][mi] = b;
        }
        for (int j = 0; j < 128; j += 4) {
            float4 a0 = *(const float4*)&s_mid[(cg * 4 + 0) * SMID_LD + j];
            float4 a1 = *(const float4*)&s_mid[(cg * 4 + 1) * SMID_LD + j];
            float4 a2 = *(const float4*)&s_mid[(cg * 4 + 2) * SMID_LD + j];
            float4 a3 = *(const float4*)&s_mid[(cg * 4 + 3) * SMID_LD + j];
            float av0[4] = {a0.x, a0.y, a0.z, a0.w};
            float av1[4] = {a1.x, a1.y, a1.z, a1.w};
            float av2[4] = {a2.x, a2.y, a2.z, a2.w};
            float av3[4] = {a3.x, a3.y, a3.z, a3.w};
#pragma unroll
            for (int q = 0; q < 4; q++) {
                float4 wlo = *(const float4*)&wo1[(j + q) * 256 + m0];
                float4 whi = *(const float4*)&wo1[(j + q) * 256 + m0 + 4];
                float wv[8] = {wlo.x, wlo.y, wlo.z, wlo.w,
                               whi.x, whi.y, whi.z, whi.w};
#pragma unroll
                for (int mi = 0; mi < 8; mi++) {
                    acc[0][mi] = fmaf(av0[q], wv[mi], acc[0][mi]);
                    acc[1][mi] = fmaf(av1[q], wv[mi], acc[1][mi]);
                    acc[2][mi] = fmaf(av2[q], wv[mi], acc[2][mi]);
                    acc[3][mi] = fmaf(av3[q], wv[mi], acc[3][mi]);
                }
            }
        }
#pragma unroll
        for (int c = 0; c < 4; c++) {
            float4 lo = make_float4(fmaxf(acc[c][0], 0.f), fmaxf(acc[c][1], 0.f),
                                    fmaxf(acc[c][2], 0.f), fmaxf(acc[c][3], 0.f));
            float4 hi = make_float4(fmaxf(acc[c][4], 0.f), fmaxf(acc[c][5], 0.f),
                                    fmaxf(acc[c][6], 0.f), fmaxf(acc[c][7], 0.f));
            size_t row = (size_t)(c0 + cg * 4 + c) * 256 + m0;
            *(float4*)&out[row + 0] = lo;
            *(float4*)&out[row + 4] = hi;
        }
    }
}

extern "C" void kernel_launch(void* const* d_in, const int* in_sizes, int n_in,
                              void* d_out, int out_size, void* d_ws, size_t ws_size,
                              hipStream_t stream)
{
    const float* pf      = (const float*)d_in[0];
    const int*   labels  = (const int*)d_in[1];
    const float* centers = (const float*)d_in[2];
    const float* points  = (const float*)d_in[3];
    const float* we0 = (const float*)d_in[4];
    const float* be0 = (const float*)d_in[5];
    const float* we1 = (const float*)d_in[6];
    const float* be1 = (const float*)d_in[7];
    const float* we2 = (const float*)d_in[8];
    const float* be2 = (const float*)d_in[9];
    const float* we3 = (const float*)d_in[10];
    const float* be3 = (const float*)d_in[11];
    const float* wa0 = (const float*)d_in[12];
    const float* ba0 = (const float*)d_in[13];
    const float* wa1 = (const float*)d_in[14];
    const float* ba1 = (const float*)d_in[15];
    const float* wo0 = (const float*)d_in[16];
    const float* bo0 = (const float*)d_in[17];
    const float* wo1 = (const float*)d_in[18];
    const float* bo1 = (const float*)d_in[19];
    float* out = (float*)d_out;

    int n = in_sizes[0] / 8;        // N points (2,000,000)
    int C = in_sizes[2] / 3;        // clusters (65,536)

    // workspace layout
    int* counts = (int*)d_ws;                   // C
    int* cursor = counts + C;                   // C
    int* off    = cursor + C;                   // C+1
    int* bsum   = off + C + 1;                  // <=256
    uintptr_t tb = ((uintptr_t)(bsum + 256) + 255) & ~(uintptr_t)255;
    unsigned short* tsort = (unsigned short*)tb; // n x 64 bf16, cluster-sorted

    hipMemsetAsync(counts, 0, (size_t)C * sizeof(int), stream);

    int pblocks = (n + TPB - 1) / TPB;
    int nb = (C + 255) / 256;                   // 256 scan blocks
    hist_kernel<<<pblocks, TPB, 0, stream>>>(labels, counts, n);
    scan_local<<<nb, 256, 0, stream>>>(counts, off, bsum, C);
    scan_base<<<1, 256, 0, stream>>>(bsum, off, nb, C);
    scan_apply<<<nb, 256, 0, stream>>>(off, cursor, bsum, C);

    point_mlp_kernel<<<pblocks, TPB, 0, stream>>>(
        pf, labels, centers, points,
        we0, be0, we1, be1, we2, be2, we3, be3,
        wa0, ba0, wa1, ba1, cursor, tsort, n);

    agg_kernel<<<C / NCB, TPB, 0, stream>>>(tsort, off, out);

    outmlp_kernel<<<C / NCB, TPB, 0, stream>>>(wo0, bo0, wo1, bo1, out);
}